// Round 1
// baseline (1236.437 us; speedup 1.0000x reference)
//
#include <hip/hip_runtime.h>
#include <hip/hip_bf16.h>

#define N_NODES 50000
#define N_EDGES 800000
#define IN_FEAT 256
#define HEADS 8
#define D_K 64
#define HD 512  // HEADS*D_K

typedef __hip_bfloat16 bf16;

// ---------------- workspace layout (bytes) ----------------
// Qb  bf16[N][512]  : 51,200,000
// Kb  bf16[N][512]  : 51,200,000
// Vb  bf16[N][512]  : 51,200,000
// offsets int[N+1]  : 200,004 (padded)
// cursor  int[N]    : 200,000
// deg     int[N]    : 200,000
// csr_col int[E]    : 3,200,000
// total ~157.4 MB
#define WS_Q       0
#define WS_K       51200000
#define WS_V       102400000
#define WS_OFFSETS 153600000
#define WS_CURSOR  153800192
#define WS_DEG     154000192
#define WS_CSR     154200192

// ---------------- QKV projection: fp32 SGEMM, bf16 output ----------------
// C[m][n] = sum_k x[m][k] * W[k][n];  A row-major [50000,256], W row-major [256,512]
// grid.x = ceil(N/128), grid.y = 12 (3 matrices x 4 col-blocks of 128)
__global__ __launch_bounds__(256) void sgemm_qkv(
    const float* __restrict__ x,
    const float* __restrict__ Wq, const float* __restrict__ Wk, const float* __restrict__ Wv,
    bf16* __restrict__ Qb, bf16* __restrict__ Kb, bf16* __restrict__ Vb)
{
    __shared__ float As[16][128];
    __shared__ float Bs[16][128];

    const int tid = threadIdx.x;
    const int m0  = blockIdx.x * 128;
    const int by  = blockIdx.y;            // 0..11
    const int wsel  = by >> 2;             // 0=Q 1=K 2=V
    const int ncol0 = (by & 3) * 128;
    const float* __restrict__ W = (wsel == 0) ? Wq : (wsel == 1) ? Wk : Wv;
    bf16* __restrict__ outp     = (wsel == 0) ? Qb : (wsel == 1) ? Kb : Vb;

    const int tx = tid & 15;   // col group
    const int ty = tid >> 4;   // row group

    float acc[8][8];
#pragma unroll
    for (int i = 0; i < 8; ++i)
#pragma unroll
        for (int j = 0; j < 8; ++j) acc[i][j] = 0.f;

    for (int k0 = 0; k0 < IN_FEAT; k0 += 16) {
        // stage A tile (128 rows x 16 k), stored transposed As[k][m]
        {
            const int k = tid & 15;
            const int mb = tid >> 4;   // 0..15
#pragma unroll
            for (int p = 0; p < 8; ++p) {
                const int m  = mb + p * 16;
                const int gm = m0 + m;
                float v = 0.f;
                if (gm < N_NODES) v = x[gm * IN_FEAT + k0 + k];
                As[k][m] = v;
            }
        }
        // stage B tile (16 k x 128 n)
        {
            const int n  = tid & 127;
            const int kb = tid >> 7;   // 0..1
#pragma unroll
            for (int p = 0; p < 8; ++p) {
                const int kk = kb + p * 2;
                Bs[kk][n] = W[(k0 + kk) * HD + ncol0 + n];
            }
        }
        __syncthreads();

#pragma unroll
        for (int k = 0; k < 16; ++k) {
            float a[8], b[8];
            *(float4*)&a[0] = *(const float4*)&As[k][ty * 8];
            *(float4*)&a[4] = *(const float4*)&As[k][ty * 8 + 4];
            *(float4*)&b[0] = *(const float4*)&Bs[k][tx * 8];
            *(float4*)&b[4] = *(const float4*)&Bs[k][tx * 8 + 4];
#pragma unroll
            for (int i = 0; i < 8; ++i)
#pragma unroll
                for (int j = 0; j < 8; ++j)
                    acc[i][j] = fmaf(a[i], b[j], acc[i][j]);
        }
        __syncthreads();
    }

    // epilogue: convert to bf16, 16B stores
#pragma unroll
    for (int i = 0; i < 8; ++i) {
        const int gm = m0 + ty * 8 + i;
        if (gm < N_NODES) {
            alignas(16) bf16 tmp[8];
#pragma unroll
            for (int j = 0; j < 8; ++j) tmp[j] = __float2bfloat16(acc[i][j]);
            *reinterpret_cast<uint4*>(outp + (size_t)gm * HD + ncol0 + tx * 8) =
                *reinterpret_cast<const uint4*>(tmp);
        }
    }
}

// ---------------- CSR build ----------------
__global__ void zero_deg_kernel(int* __restrict__ deg)
{
    int i = blockIdx.x * 256 + threadIdx.x;
    if (i < N_NODES) deg[i] = 0;
}

__global__ void hist_kernel(const int* __restrict__ row, int* __restrict__ deg)
{
    int e = blockIdx.x * 256 + threadIdx.x;
    if (e < N_EDGES) atomicAdd(&deg[row[e]], 1);
}

// single-block exclusive scan over 50000 degrees
__global__ __launch_bounds__(1024) void scan_kernel(const int* __restrict__ deg,
                                                    int* __restrict__ offsets,
                                                    int* __restrict__ cursor)
{
    __shared__ int buf[1024];
    const int tid = threadIdx.x;
    int carry = 0;
    for (int base = 0; base < N_NODES; base += 1024) {
        const int i = base + tid;
        const int v = (i < N_NODES) ? deg[i] : 0;
        buf[tid] = v;
        __syncthreads();
        for (int off = 1; off < 1024; off <<= 1) {
            int t = (tid >= off) ? buf[tid - off] : 0;
            __syncthreads();
            buf[tid] += t;
            __syncthreads();
        }
        const int excl = buf[tid] - v;
        if (i < N_NODES) {
            offsets[i] = carry + excl;
            cursor[i]  = carry + excl;
        }
        carry += buf[1023];
        __syncthreads();
    }
    if (tid == 0) offsets[N_NODES] = carry;
}

__global__ void scatter_kernel(const int* __restrict__ row, const int* __restrict__ col,
                               int* __restrict__ cursor, int* __restrict__ csr_col)
{
    int e = blockIdx.x * 256 + threadIdx.x;
    if (e < N_EDGES) {
        const int pos = atomicAdd(&cursor[row[e]], 1);
        csr_col[pos] = col[e];
    }
}

// ---------------- fused edge phase ----------------
// one wave per (node r, head h); lane = feature dim d (64 = D_K = wave size)
// online softmax over incoming edges of r; output written directly (no atomics)
__global__ __launch_bounds__(256) void edge_attn(
    const bf16* __restrict__ Qb, const bf16* __restrict__ Kb, const bf16* __restrict__ Vb,
    const float* __restrict__ Dm,
    const int* __restrict__ offsets, const int* __restrict__ csr_col,
    float* __restrict__ out)
{
    const int tid  = threadIdx.x;
    const int lane = tid & 63;
    const int wid  = tid >> 6;
    const int task = blockIdx.x * 4 + wid;   // < N*H by construction
    const int r = task >> 3;
    const int h = task & 7;

    const int base = h * D_K + lane;
    const float kd = __bfloat162float(Kb[r * HD + base]);
    const float Dv = Dm[base];
    const int s0 = offsets[r];
    const int s1 = offsets[r + 1];
    const float scale = 0.125f;   // 1/sqrt(64)

    float m = -INFINITY, l = 0.f, o = 0.f;

    for (int j0 = s0; j0 < s1; j0 += 64) {
        const int myj = j0 + lane;
        const int myc = (myj < s1) ? csr_col[myj] : 0;
        const int cnt = min(64, s1 - j0);
        for (int jj = 0; jj < cnt; ++jj) {
            const int c = __shfl(myc, jj, 64);
            const float q = __bfloat162float(Qb[c * HD + base]);
            const float v = __bfloat162float(Vb[c * HD + base]);
            const float diff = kd - q;
            const float t = (c == r) ? (kd * q) : (diff * diff);
            float p = Dv * t;
            p += __shfl_xor(p, 1, 64);
            p += __shfl_xor(p, 2, 64);
            p += __shfl_xor(p, 4, 64);
            p += __shfl_xor(p, 8, 64);
            p += __shfl_xor(p, 16, 64);
            p += __shfl_xor(p, 32, 64);
            float s = p * scale;
            s = (s < 0.f) ? 0.2f * s : s;          // leaky_relu 0.2
            const float mn  = fmaxf(m, s);
            const float corr = __expf(m - mn);     // exp(-inf)=0 on first edge
            const float w    = __expf(s - mn);
            l = l * corr + w;
            o = fmaf(o, corr, w * v);
            m = mn;
        }
    }
    out[(size_t)r * HD + base] = o / (l + 1e-16f);
}

// ---------------- launcher ----------------
extern "C" void kernel_launch(void* const* d_in, const int* in_sizes, int n_in,
                              void* d_out, int out_size, void* d_ws, size_t ws_size,
                              hipStream_t stream)
{
    const float* x  = (const float*)d_in[0];
    const int*   ei = (const int*)d_in[1];
    const float* Wq = (const float*)d_in[2];
    const float* Wk = (const float*)d_in[3];
    const float* Wv = (const float*)d_in[4];
    const float* Dm = (const float*)d_in[5];
    float* out = (float*)d_out;

    char* ws = (char*)d_ws;
    bf16* Qb      = (bf16*)(ws + WS_Q);
    bf16* Kb      = (bf16*)(ws + WS_K);
    bf16* Vb      = (bf16*)(ws + WS_V);
    int*  offsets = (int*)(ws + WS_OFFSETS);
    int*  cursor  = (int*)(ws + WS_CURSOR);
    int*  deg     = (int*)(ws + WS_DEG);
    int*  csr_col = (int*)(ws + WS_CSR);

    const int* row = ei;             // edge_index[0]
    const int* col = ei + N_EDGES;   // edge_index[1]

    hipLaunchKernelGGL(zero_deg_kernel, dim3((N_NODES + 255) / 256), dim3(256), 0, stream, deg);
    hipLaunchKernelGGL(sgemm_qkv, dim3((N_NODES + 127) / 128, 12), dim3(256), 0, stream,
                       x, Wq, Wk, Wv, Qb, Kb, Vb);
    hipLaunchKernelGGL(hist_kernel, dim3((N_EDGES + 255) / 256), dim3(256), 0, stream, row, deg);
    hipLaunchKernelGGL(scan_kernel, dim3(1), dim3(1024), 0, stream, deg, offsets, cursor);
    hipLaunchKernelGGL(scatter_kernel, dim3((N_EDGES + 255) / 256), dim3(256), 0, stream,
                       row, col, cursor, csr_col);
    hipLaunchKernelGGL(edge_attn, dim3(N_NODES * HEADS / 4), dim3(256), 0, stream,
                       Qb, Kb, Vb, Dm, offsets, csr_col, out);
}

// Round 2
// 946.951 us; speedup vs baseline: 1.3057x; 1.3057x over previous
//
#include <hip/hip_runtime.h>
#include <hip/hip_bf16.h>

#define N_NODES 50000
#define N_EDGES 800000
#define IN_FEAT 256
#define HEADS 8
#define D_K 64
#define HD 512  // HEADS*D_K

typedef __hip_bfloat16 bf16;
typedef unsigned int u32;

// ---------------- workspace layout (bytes) ----------------
#define WS_Q       0
#define WS_K       51200000
#define WS_V       102400000
#define WS_OFFSETS 153600000
#define WS_CURSOR  153800192
#define WS_DEG     154000192
#define WS_CSR     154200192
#define WS_SQ2     157400192   // float[N*8] -> ends 159,000,192

__device__ __forceinline__ float bflo(u32 u) { return __uint_as_float(u << 16); }
__device__ __forceinline__ float bfhi(u32 u) { return __uint_as_float(u & 0xffff0000u); }

// ---------------- QKV projection: fp32 SGEMM, bf16 output (unchanged) ----------------
__global__ __launch_bounds__(256) void sgemm_qkv(
    const float* __restrict__ x,
    const float* __restrict__ Wq, const float* __restrict__ Wk, const float* __restrict__ Wv,
    bf16* __restrict__ Qb, bf16* __restrict__ Kb, bf16* __restrict__ Vb)
{
    __shared__ float As[16][128];
    __shared__ float Bs[16][128];

    const int tid = threadIdx.x;
    const int m0  = blockIdx.x * 128;
    const int by  = blockIdx.y;            // 0..11
    const int wsel  = by >> 2;             // 0=Q 1=K 2=V
    const int ncol0 = (by & 3) * 128;
    const float* __restrict__ W = (wsel == 0) ? Wq : (wsel == 1) ? Wk : Wv;
    bf16* __restrict__ outp     = (wsel == 0) ? Qb : (wsel == 1) ? Kb : Vb;

    const int tx = tid & 15;
    const int ty = tid >> 4;

    float acc[8][8];
#pragma unroll
    for (int i = 0; i < 8; ++i)
#pragma unroll
        for (int j = 0; j < 8; ++j) acc[i][j] = 0.f;

    for (int k0 = 0; k0 < IN_FEAT; k0 += 16) {
        {
            const int k = tid & 15;
            const int mb = tid >> 4;
#pragma unroll
            for (int p = 0; p < 8; ++p) {
                const int m  = mb + p * 16;
                const int gm = m0 + m;
                float v = 0.f;
                if (gm < N_NODES) v = x[gm * IN_FEAT + k0 + k];
                As[k][m] = v;
            }
        }
        {
            const int n  = tid & 127;
            const int kb = tid >> 7;
#pragma unroll
            for (int p = 0; p < 8; ++p) {
                const int kk = kb + p * 2;
                Bs[kk][n] = W[(k0 + kk) * HD + ncol0 + n];
            }
        }
        __syncthreads();

#pragma unroll
        for (int k = 0; k < 16; ++k) {
            float a[8], b[8];
            *(float4*)&a[0] = *(const float4*)&As[k][ty * 8];
            *(float4*)&a[4] = *(const float4*)&As[k][ty * 8 + 4];
            *(float4*)&b[0] = *(const float4*)&Bs[k][tx * 8];
            *(float4*)&b[4] = *(const float4*)&Bs[k][tx * 8 + 4];
#pragma unroll
            for (int i = 0; i < 8; ++i)
#pragma unroll
                for (int j = 0; j < 8; ++j)
                    acc[i][j] = fmaf(a[i], b[j], acc[i][j]);
        }
        __syncthreads();
    }

#pragma unroll
    for (int i = 0; i < 8; ++i) {
        const int gm = m0 + ty * 8 + i;
        if (gm < N_NODES) {
            alignas(16) bf16 tmp[8];
#pragma unroll
            for (int j = 0; j < 8; ++j) tmp[j] = __float2bfloat16(acc[i][j]);
            *reinterpret_cast<uint4*>(outp + (size_t)gm * HD + ncol0 + tx * 8) =
                *reinterpret_cast<const uint4*>(tmp);
        }
    }
}

// ---------------- CSR build (unchanged) ----------------
__global__ void zero_deg_kernel(int* __restrict__ deg)
{
    int i = blockIdx.x * 256 + threadIdx.x;
    if (i < N_NODES) deg[i] = 0;
}

__global__ void hist_kernel(const int* __restrict__ row, int* __restrict__ deg)
{
    int e = blockIdx.x * 256 + threadIdx.x;
    if (e < N_EDGES) atomicAdd(&deg[row[e]], 1);
}

__global__ __launch_bounds__(1024) void scan_kernel(const int* __restrict__ deg,
                                                    int* __restrict__ offsets,
                                                    int* __restrict__ cursor)
{
    __shared__ int buf[1024];
    const int tid = threadIdx.x;
    int carry = 0;
    for (int base = 0; base < N_NODES; base += 1024) {
        const int i = base + tid;
        const int v = (i < N_NODES) ? deg[i] : 0;
        buf[tid] = v;
        __syncthreads();
        for (int off = 1; off < 1024; off <<= 1) {
            int t = (tid >= off) ? buf[tid - off] : 0;
            __syncthreads();
            buf[tid] += t;
            __syncthreads();
        }
        const int excl = buf[tid] - v;
        if (i < N_NODES) {
            offsets[i] = carry + excl;
            cursor[i]  = carry + excl;
        }
        carry += buf[1023];
        __syncthreads();
    }
    if (tid == 0) offsets[N_NODES] = carry;
}

__global__ void scatter_kernel(const int* __restrict__ row, const int* __restrict__ col,
                               int* __restrict__ cursor, int* __restrict__ csr_col)
{
    int e = blockIdx.x * 256 + threadIdx.x;
    if (e < N_EDGES) {
        const int pos = atomicAdd(&cursor[row[e]], 1);
        csr_col[pos] = col[e];
    }
}

// ---------------- sQ2 precompute: sQ2[c,h] = sum_d D[h,d]*Q[c,h,d]^2 ----------------
// one wave per node; lane covers dims [8*lane, 8*lane+8)
__global__ __launch_bounds__(256) void sq2_kernel(
    const bf16* __restrict__ Qb, const float* __restrict__ Dm, float* __restrict__ sQ2)
{
    const int lane = threadIdx.x & 63;
    const int wid  = threadIdx.x >> 6;
    const int n = blockIdx.x * 4 + wid;
    if (n >= N_NODES) return;

    uint4 qp = *(const uint4*)(Qb + (size_t)n * HD + lane * 8);
    float4 da = *(const float4*)(Dm + lane * 8);
    float4 db = *(const float4*)(Dm + lane * 8 + 4);
    float q0 = bflo(qp.x), q1 = bfhi(qp.x), q2 = bflo(qp.y), q3 = bfhi(qp.y);
    float q4 = bflo(qp.z), q5 = bfhi(qp.z), q6 = bflo(qp.w), q7 = bfhi(qp.w);
    float s = da.x*q0*q0 + da.y*q1*q1 + da.z*q2*q2 + da.w*q3*q3
            + db.x*q4*q4 + db.y*q5*q5 + db.z*q6*q6 + db.w*q7*q7;
    s += __shfl_xor(s, 1, 64);
    s += __shfl_xor(s, 2, 64);
    s += __shfl_xor(s, 4, 64);
    if ((lane & 7) == 0) sQ2[n * 8 + (lane >> 3)] = s;
}

// ---------------- fused edge phase: one wave per node, all 8 heads ----------------
// Phase A: lane = j*8+h scores (edge j, head h); dot via expanded Mahalanobis.
// Phase B: lane = dim/8; one coalesced V-row load per edge covers all heads.
__global__ __launch_bounds__(256) void edge_attn(
    const bf16* __restrict__ Qb, const bf16* __restrict__ Kb, const bf16* __restrict__ Vb,
    const float* __restrict__ Dm, const float* __restrict__ sQ2,
    const int* __restrict__ offsets, const int* __restrict__ csr_col,
    float* __restrict__ out)
{
    __shared__ float dk_lds[4][8][72];   // [wave][head][64 dims + pad]

    const int tid  = threadIdx.x;
    const int lane = tid & 63;
    const int wid  = tid >> 6;
    const int r = blockIdx.x * 4 + wid;
    if (r >= N_NODES) return;

    // ---- init: DK = D*K[r] into LDS (phase-B layout), sK2 per head ----
    const int hB = lane >> 3;        // head in B-layout
    const int tB = lane & 7;         // 8-dim chunk within head
    uint4 kp = *(const uint4*)(Kb + (size_t)r * HD + lane * 8);
    float4 da = *(const float4*)(Dm + lane * 8);
    float4 db = *(const float4*)(Dm + lane * 8 + 4);
    float k0 = bflo(kp.x), k1 = bfhi(kp.x), k2 = bflo(kp.y), k3 = bfhi(kp.y);
    float k4 = bflo(kp.z), k5 = bfhi(kp.z), k6 = bflo(kp.w), k7 = bfhi(kp.w);
    float e0_ = da.x*k0, e1_ = da.y*k1, e2_ = da.z*k2, e3_ = da.w*k3;
    float e4_ = db.x*k4, e5_ = db.y*k5, e6_ = db.z*k6, e7_ = db.w*k7;
    float sk = e0_*k0 + e1_*k1 + e2_*k2 + e3_*k3 + e4_*k4 + e5_*k5 + e6_*k6 + e7_*k7;
    sk += __shfl_xor(sk, 1, 64);
    sk += __shfl_xor(sk, 2, 64);
    sk += __shfl_xor(sk, 4, 64);     // sK2 for head hB, on every lane
    float4 w0 = {e0_, e1_, e2_, e3_}, w1 = {e4_, e5_, e6_, e7_};
    *(float4*)&dk_lds[wid][hB][tB * 8]     = w0;
    *(float4*)&dk_lds[wid][hB][tB * 8 + 4] = w1;

    const int hA = lane & 7;         // head in A-layout
    const int jA = lane >> 3;        // edge slot in A-layout
    const float sK2_A = __shfl(sk, hA * 8, 64);

    const int s0 = offsets[r];
    const int s1 = offsets[r + 1];

    float m = -INFINITY, l = 0.f;
    float o0=0,o1=0,o2=0,o3=0,o4=0,o5=0,o6=0,o7=0;

    const float* dkrow = &dk_lds[wid][hA][0];

    for (int eb = s0; eb < s1; eb += 8) {
        const int cnt = min(8, s1 - eb);
        const bool act = jA < cnt;
        const int cj = csr_col[eb + min(jA, cnt - 1)];

        // ---- phase A: cross = sum_d DK[hA][d] * Q[cj, hA*64+d] ----
        const bf16* qrow = Qb + (size_t)cj * HD + hA * D_K;
        float cross = 0.f;
#pragma unroll
        for (int t = 0; t < 8; ++t) {
            uint4 qp = *(const uint4*)(qrow + t * 8);
            float4 ka = *(const float4*)(dkrow + t * 8);
            float4 kb2 = *(const float4*)(dkrow + t * 8 + 4);
            cross += ka.x * bflo(qp.x) + ka.y * bfhi(qp.x)
                   + ka.z * bflo(qp.y) + ka.w * bfhi(qp.y)
                   + kb2.x * bflo(qp.z) + kb2.y * bfhi(qp.z)
                   + kb2.z * bflo(qp.w) + kb2.w * bfhi(qp.w);
        }
        const float sq2 = sQ2[cj * 8 + hA];
        float sraw = (cj == r) ? cross : (sK2_A - 2.f * cross + sq2);
        float s = sraw * 0.125f;
        s = (s < 0.f) ? 0.2f * s : s;
        s = act ? s : -INFINITY;

        // ---- online softmax (per-head butterfly over edge slots) ----
        float bm = s;
        bm = fmaxf(bm, __shfl_xor(bm, 8, 64));
        bm = fmaxf(bm, __shfl_xor(bm, 16, 64));
        bm = fmaxf(bm, __shfl_xor(bm, 32, 64));
        const float mn   = fmaxf(m, bm);
        const float corr = __expf(m - mn);    // exp(-inf)=0 on first pass
        const float w    = __expf(s - mn);    // 0 for inactive lanes
        m = mn;
        float ls = w;
        ls += __shfl_xor(ls, 8, 64);
        ls += __shfl_xor(ls, 16, 64);
        ls += __shfl_xor(ls, 32, 64);
        l = l * corr + ls;

        // ---- phase B: o[d] += alpha_e * V[c_e, d], lane = dim/8 ----
        const float corrB = __shfl(corr, hB, 64);
        o0*=corrB; o1*=corrB; o2*=corrB; o3*=corrB;
        o4*=corrB; o5*=corrB; o6*=corrB; o7*=corrB;
#pragma unroll
        for (int e = 0; e < 8; ++e) {
            const int   ce    = __shfl(cj, e * 8, 64);
            const float alpha = __shfl(w, e * 8 + hB, 64);   // 0 for e >= cnt
            uint4 vp = *(const uint4*)(Vb + (size_t)ce * HD + lane * 8);
            o0 = fmaf(alpha, bflo(vp.x), o0);
            o1 = fmaf(alpha, bfhi(vp.x), o1);
            o2 = fmaf(alpha, bflo(vp.y), o2);
            o3 = fmaf(alpha, bfhi(vp.y), o3);
            o4 = fmaf(alpha, bflo(vp.z), o4);
            o5 = fmaf(alpha, bfhi(vp.z), o5);
            o6 = fmaf(alpha, bflo(vp.w), o6);
            o7 = fmaf(alpha, bfhi(vp.w), o7);
        }
    }

    const float lB  = __shfl(l, hB, 64);
    const float inv = 1.f / (lB + 1e-16f);
    float4 r0 = {o0*inv, o1*inv, o2*inv, o3*inv};
    float4 r1 = {o4*inv, o5*inv, o6*inv, o7*inv};
    *(float4*)(out + (size_t)r * HD + lane * 8)     = r0;
    *(float4*)(out + (size_t)r * HD + lane * 8 + 4) = r1;
}

// ---------------- launcher ----------------
extern "C" void kernel_launch(void* const* d_in, const int* in_sizes, int n_in,
                              void* d_out, int out_size, void* d_ws, size_t ws_size,
                              hipStream_t stream)
{
    const float* x  = (const float*)d_in[0];
    const int*   ei = (const int*)d_in[1];
    const float* Wq = (const float*)d_in[2];
    const float* Wk = (const float*)d_in[3];
    const float* Wv = (const float*)d_in[4];
    const float* Dm = (const float*)d_in[5];
    float* out = (float*)d_out;

    char* ws = (char*)d_ws;
    bf16* Qb      = (bf16*)(ws + WS_Q);
    bf16* Kb      = (bf16*)(ws + WS_K);
    bf16* Vb      = (bf16*)(ws + WS_V);
    int*  offsets = (int*)(ws + WS_OFFSETS);
    int*  cursor  = (int*)(ws + WS_CURSOR);
    int*  deg     = (int*)(ws + WS_DEG);
    int*  csr_col = (int*)(ws + WS_CSR);
    float* sQ2    = (float*)(ws + WS_SQ2);

    const int* row = ei;
    const int* col = ei + N_EDGES;

    hipLaunchKernelGGL(zero_deg_kernel, dim3((N_NODES + 255) / 256), dim3(256), 0, stream, deg);
    hipLaunchKernelGGL(sgemm_qkv, dim3((N_NODES + 127) / 128, 12), dim3(256), 0, stream,
                       x, Wq, Wk, Wv, Qb, Kb, Vb);
    hipLaunchKernelGGL(hist_kernel, dim3((N_EDGES + 255) / 256), dim3(256), 0, stream, row, deg);
    hipLaunchKernelGGL(scan_kernel, dim3(1), dim3(1024), 0, stream, deg, offsets, cursor);
    hipLaunchKernelGGL(scatter_kernel, dim3((N_EDGES + 255) / 256), dim3(256), 0, stream,
                       row, col, cursor, csr_col);
    hipLaunchKernelGGL(sq2_kernel, dim3((N_NODES + 3) / 4), dim3(256), 0, stream, Qb, Dm, sQ2);
    hipLaunchKernelGGL(edge_attn, dim3((N_NODES + 3) / 4), dim3(256), 0, stream,
                       Qb, Kb, Vb, Dm, sQ2, offsets, csr_col, out);
}

// Round 3
// 458.214 us; speedup vs baseline: 2.6984x; 2.0666x over previous
//
#include <hip/hip_runtime.h>
#include <hip/hip_bf16.h>

#define N_NODES 50000
#define N_PAD   50176    // padded rows for GEMM staging (multiple of 128)
#define N_EDGES 800000
#define IN_FEAT 256
#define HEADS 8
#define D_K 64
#define HD 512  // HEADS*D_K

typedef __hip_bfloat16 bf16;
typedef unsigned int u32;

using bf16x8 = __attribute__((ext_vector_type(8))) short;
using f32x4  = __attribute__((ext_vector_type(4))) float;

// ---------------- workspace layout (bytes) ----------------
#define WS_Q       0
#define WS_K       51200000
#define WS_V       102400000
#define WS_OFFSETS 153600000
#define WS_CURSOR  153800192
#define WS_DEG     154000192
#define WS_CSR     154200192
#define WS_SQ2     157400192
#define WS_AUX     159000192   // int[64] scan partials

// d_out used as scratch before edge_attn overwrites it entirely:
//   xb bf16[50176][256] = 25,690,112 B at offset 0
//   Wt bf16[3][512][256] = 786,432 B at offset 25,690,112
#define DOUT_XB 0
#define DOUT_WT 25690112

#define SCAN_BLOCKS 49   // ceil(50000/1024)

__device__ __forceinline__ float bflo(u32 u) { return __uint_as_float(u << 16); }
__device__ __forceinline__ float bfhi(u32 u) { return __uint_as_float(u & 0xffff0000u); }

__device__ __forceinline__ void gload16(const void* g, void* l)
{
    __builtin_amdgcn_global_load_lds(
        (const __attribute__((address_space(1))) unsigned int*)g,
        (__attribute__((address_space(3))) unsigned int*)l,
        16, 0, 0);
}

// ---------------- input conversion ----------------
// xb[row][k] bf16, rows >= N_NODES zero-filled
__global__ __launch_bounds__(256) void convert_x(
    const float* __restrict__ x, bf16* __restrict__ xb)
{
    const int t   = blockIdx.x * 256 + threadIdx.x;   // 50176*32 threads
    const int row = t >> 5;
    const int c8  = (t & 31) * 8;
    if (row >= N_PAD) return;
    alignas(16) bf16 tmp[8];
    if (row < N_NODES) {
        const float* p = x + (size_t)row * IN_FEAT + c8;
        float4 a = *(const float4*)p;
        float4 b = *(const float4*)(p + 4);
        tmp[0] = __float2bfloat16(a.x); tmp[1] = __float2bfloat16(a.y);
        tmp[2] = __float2bfloat16(a.z); tmp[3] = __float2bfloat16(a.w);
        tmp[4] = __float2bfloat16(b.x); tmp[5] = __float2bfloat16(b.y);
        tmp[6] = __float2bfloat16(b.z); tmp[7] = __float2bfloat16(b.w);
    } else {
#pragma unroll
        for (int i = 0; i < 8; ++i) tmp[i] = __float2bfloat16(0.f);
    }
    *(uint4*)(xb + (size_t)row * IN_FEAT + c8) = *(const uint4*)tmp;
}

// Wt[mat][n][k] = W_mat[k][n], bf16
__global__ __launch_bounds__(256) void convert_w(
    const float* __restrict__ Wq, const float* __restrict__ Wk, const float* __restrict__ Wv,
    bf16* __restrict__ Wt)
{
    const int t = blockIdx.x * 256 + threadIdx.x;
    if (t >= 3 * 512 * 256) return;
    const int mat = t >> 17;
    const int r   = t & 131071;
    const int n   = r >> 8;
    const int k   = r & 255;
    const float* W = (mat == 0) ? Wq : (mat == 1) ? Wk : Wv;
    Wt[t] = __float2bfloat16(W[k * HD + n]);
}

// ---------------- MFMA bf16 QKV GEMM ----------------
// C[m][n] = sum_k xb[m][k] * Wt[mat][n][k]
// 128x128 tile, BK=32, 4 waves (2x2), each wave 64x64 = 4x4 frags of 16x16x32.
// LDS XOR slot-swizzle: phys_slot = data_slot ^ (row&3), applied on both the
// pre-swizzled global source (linear global_load_lds dest) and the ds_read.
__global__ __launch_bounds__(256) void mfma_qkv(
    const bf16* __restrict__ xb, const bf16* __restrict__ Wt,
    bf16* __restrict__ Qb, bf16* __restrict__ Kb, bf16* __restrict__ Vb)
{
    __shared__ uint4 Ab4[512];   // 8 KiB: A tile 128x32 bf16 (row stride 64 B)
    __shared__ uint4 Bb4[512];   // 8 KiB: B^T tile 128x32 bf16
    char* AbB = (char*)Ab4;
    char* BbB = (char*)Bb4;

    const int tid  = threadIdx.x;
    const int lane = tid & 63;
    const int wid  = tid >> 6;
    const int wr   = wid >> 1;
    const int wc   = wid & 1;

    const int m0  = blockIdx.x * 128;
    const int n0  = blockIdx.y * 128;
    const int mat = blockIdx.z;
    const bf16* __restrict__ wt = Wt + (size_t)mat * 512 * 256;
    bf16* __restrict__ outp = (mat == 0) ? Qb : (mat == 1) ? Kb : Vb;

    // staging geometry: chunk c covers LDS bytes [c*1024, +1024) = rows c*16..+16
    const int rch  = lane >> 2;                    // row within chunk
    const int slot = (lane & 3) ^ (rch & 3);       // pre-swizzled source k-slot
    const int sc0  = wid;                          // this wave's chunks
    const int sc1  = wid + 4;
    const size_t arow0 = (size_t)(m0 + sc0 * 16 + rch) * IN_FEAT + slot * 8;
    const size_t arow1 = (size_t)(m0 + sc1 * 16 + rch) * IN_FEAT + slot * 8;
    const size_t brow0 = (size_t)(n0 + sc0 * 16 + rch) * IN_FEAT + slot * 8;
    const size_t brow1 = (size_t)(n0 + sc1 * 16 + rch) * IN_FEAT + slot * 8;

    // fragment-read geometry
    const int fr    = lane & 15;                               // row within frag
    const int fslot = (((lane >> 4) ^ (lane & 3)) << 4);       // swizzled 16B slot
    const int abase = (wr * 64 + fr) * 64 + fslot;
    const int bbase = (wc * 64 + fr) * 64 + fslot;

    f32x4 acc[4][4];
#pragma unroll
    for (int i = 0; i < 4; ++i)
#pragma unroll
        for (int j = 0; j < 4; ++j) acc[i][j] = {0.f, 0.f, 0.f, 0.f};

    for (int k0 = 0; k0 < IN_FEAT; k0 += 32) {
        gload16(xb + arow0 + k0, AbB + sc0 * 1024);
        gload16(xb + arow1 + k0, AbB + sc1 * 1024);
        gload16(wt + brow0 + k0, BbB + sc0 * 1024);
        gload16(wt + brow1 + k0, BbB + sc1 * 1024);
        __syncthreads();

        bf16x8 aF[4], bF[4];
#pragma unroll
        for (int m = 0; m < 4; ++m) aF[m] = *(const bf16x8*)(AbB + abase + m * 16 * 64);
#pragma unroll
        for (int n = 0; n < 4; ++n) bF[n] = *(const bf16x8*)(BbB + bbase + n * 16 * 64);
#pragma unroll
        for (int m = 0; m < 4; ++m)
#pragma unroll
            for (int n = 0; n < 4; ++n)
                acc[m][n] = __builtin_amdgcn_mfma_f32_16x16x32_bf16(aF[m], bF[n], acc[m][n], 0, 0, 0);
        __syncthreads();
    }

    // epilogue: C/D mapping col = lane&15, row = (lane>>4)*4 + j
    const int c_col = lane & 15;
    const int r_hi  = (lane >> 4) * 4;
#pragma unroll
    for (int m = 0; m < 4; ++m) {
        const int grow_base = m0 + wr * 64 + m * 16 + r_hi;
#pragma unroll
        for (int j = 0; j < 4; ++j) {
            const int grow = grow_base + j;
            if (grow < N_NODES) {
#pragma unroll
                for (int n = 0; n < 4; ++n)
                    outp[(size_t)grow * HD + n0 + wc * 64 + n * 16 + c_col] =
                        __float2bfloat16(acc[m][n][j]);
            }
        }
    }
}

// ---------------- CSR build ----------------
__global__ void zero_deg_kernel(int* __restrict__ deg)
{
    int i = blockIdx.x * 256 + threadIdx.x;
    if (i < N_NODES) deg[i] = 0;
}

__global__ void hist_kernel(const int* __restrict__ row, int* __restrict__ deg)
{
    int e = blockIdx.x * 256 + threadIdx.x;
    if (e < N_EDGES) atomicAdd(&deg[row[e]], 1);
}

// hierarchical scan: local scan -> aux scan -> apply
__global__ __launch_bounds__(1024) void scan_local(const int* __restrict__ deg,
                                                   int* __restrict__ offsets,
                                                   int* __restrict__ aux)
{
    __shared__ int buf[1024];
    const int tid = threadIdx.x;
    const int i = blockIdx.x * 1024 + tid;
    const int v = (i < N_NODES) ? deg[i] : 0;
    buf[tid] = v;
    __syncthreads();
    for (int off = 1; off < 1024; off <<= 1) {
        int t = (tid >= off) ? buf[tid - off] : 0;
        __syncthreads();
        buf[tid] += t;
        __syncthreads();
    }
    if (i < N_NODES) offsets[i] = buf[tid] - v;
    if (tid == 1023) aux[blockIdx.x] = buf[1023];
}

__global__ void scan_aux(int* __restrict__ aux)   // 1 block, 64 threads (1 wave)
{
    const int tid = threadIdx.x;
    const int orig = (tid < SCAN_BLOCKS) ? aux[tid] : 0;
    int v = orig;
    for (int off = 1; off < 64; off <<= 1) {
        int t = __shfl_up(v, off, 64);
        if (tid >= off) v += t;
    }
    if (tid < SCAN_BLOCKS) aux[tid] = v - orig;   // exclusive
}

__global__ __launch_bounds__(1024) void scan_apply(const int* __restrict__ aux,
                                                   int* __restrict__ offsets,
                                                   int* __restrict__ cursor)
{
    const int i = blockIdx.x * 1024 + threadIdx.x;
    if (i < N_NODES) {
        const int off = offsets[i] + aux[i >> 10];
        offsets[i] = off;
        cursor[i]  = off;
    }
    if (i == 0) offsets[N_NODES] = N_EDGES;
}

__global__ void scatter_kernel(const int* __restrict__ row, const int* __restrict__ col,
                               int* __restrict__ cursor, int* __restrict__ csr_col)
{
    int e = blockIdx.x * 256 + threadIdx.x;
    if (e < N_EDGES) {
        const int pos = atomicAdd(&cursor[row[e]], 1);
        csr_col[pos] = col[e];
    }
}

// ---------------- sQ2 precompute ----------------
__global__ __launch_bounds__(256) void sq2_kernel(
    const bf16* __restrict__ Qb, const float* __restrict__ Dm, float* __restrict__ sQ2)
{
    const int lane = threadIdx.x & 63;
    const int wid  = threadIdx.x >> 6;
    const int n = blockIdx.x * 4 + wid;
    if (n >= N_NODES) return;

    uint4 qp = *(const uint4*)(Qb + (size_t)n * HD + lane * 8);
    float4 da = *(const float4*)(Dm + lane * 8);
    float4 db = *(const float4*)(Dm + lane * 8 + 4);
    float q0 = bflo(qp.x), q1 = bfhi(qp.x), q2 = bflo(qp.y), q3 = bfhi(qp.y);
    float q4 = bflo(qp.z), q5 = bfhi(qp.z), q6 = bflo(qp.w), q7 = bfhi(qp.w);
    float s = da.x*q0*q0 + da.y*q1*q1 + da.z*q2*q2 + da.w*q3*q3
            + db.x*q4*q4 + db.y*q5*q5 + db.z*q6*q6 + db.w*q7*q7;
    s += __shfl_xor(s, 1, 64);
    s += __shfl_xor(s, 2, 64);
    s += __shfl_xor(s, 4, 64);
    if ((lane & 7) == 0) sQ2[n * 8 + (lane >> 3)] = s;
}

// ---------------- fused edge phase (unchanged from round 2) ----------------
__global__ __launch_bounds__(256) void edge_attn(
    const bf16* __restrict__ Qb, const bf16* __restrict__ Kb, const bf16* __restrict__ Vb,
    const float* __restrict__ Dm, const float* __restrict__ sQ2,
    const int* __restrict__ offsets, const int* __restrict__ csr_col,
    float* __restrict__ out)
{
    __shared__ float dk_lds[4][8][72];

    const int tid  = threadIdx.x;
    const int lane = tid & 63;
    const int wid  = tid >> 6;
    const int r = blockIdx.x * 4 + wid;
    if (r >= N_NODES) return;

    const int hB = lane >> 3;
    const int tB = lane & 7;
    uint4 kp = *(const uint4*)(Kb + (size_t)r * HD + lane * 8);
    float4 da = *(const float4*)(Dm + lane * 8);
    float4 db = *(const float4*)(Dm + lane * 8 + 4);
    float k0 = bflo(kp.x), k1 = bfhi(kp.x), k2 = bflo(kp.y), k3 = bfhi(kp.y);
    float k4 = bflo(kp.z), k5 = bfhi(kp.z), k6 = bflo(kp.w), k7 = bfhi(kp.w);
    float e0_ = da.x*k0, e1_ = da.y*k1, e2_ = da.z*k2, e3_ = da.w*k3;
    float e4_ = db.x*k4, e5_ = db.y*k5, e6_ = db.z*k6, e7_ = db.w*k7;
    float sk = e0_*k0 + e1_*k1 + e2_*k2 + e3_*k3 + e4_*k4 + e5_*k5 + e6_*k6 + e7_*k7;
    sk += __shfl_xor(sk, 1, 64);
    sk += __shfl_xor(sk, 2, 64);
    sk += __shfl_xor(sk, 4, 64);
    float4 w0 = {e0_, e1_, e2_, e3_}, w1 = {e4_, e5_, e6_, e7_};
    *(float4*)&dk_lds[wid][hB][tB * 8]     = w0;
    *(float4*)&dk_lds[wid][hB][tB * 8 + 4] = w1;

    const int hA = lane & 7;
    const int jA = lane >> 3;
    const float sK2_A = __shfl(sk, hA * 8, 64);

    const int s0 = offsets[r];
    const int s1 = offsets[r + 1];

    float m = -INFINITY, l = 0.f;
    float o0=0,o1=0,o2=0,o3=0,o4=0,o5=0,o6=0,o7=0;

    const float* dkrow = &dk_lds[wid][hA][0];

    for (int eb = s0; eb < s1; eb += 8) {
        const int cnt = min(8, s1 - eb);
        const bool act = jA < cnt;
        const int cj = csr_col[eb + min(jA, cnt - 1)];

        const bf16* qrow = Qb + (size_t)cj * HD + hA * D_K;
        float cross = 0.f;
#pragma unroll
        for (int t = 0; t < 8; ++t) {
            uint4 qp = *(const uint4*)(qrow + t * 8);
            float4 ka = *(const float4*)(dkrow + t * 8);
            float4 kb2 = *(const float4*)(dkrow + t * 8 + 4);
            cross += ka.x * bflo(qp.x) + ka.y * bfhi(qp.x)
                   + ka.z * bflo(qp.y) + ka.w * bfhi(qp.y)
                   + kb2.x * bflo(qp.z) + kb2.y * bfhi(qp.z)
                   + kb2.z * bflo(qp.w) + kb2.w * bfhi(qp.w);
        }
        const float sq2 = sQ2[cj * 8 + hA];
        float sraw = (cj == r) ? cross : (sK2_A - 2.f * cross + sq2);
        float s = sraw * 0.125f;
        s = (s < 0.f) ? 0.2f * s : s;
        s = act ? s : -INFINITY;

        float bm = s;
        bm = fmaxf(bm, __shfl_xor(bm, 8, 64));
        bm = fmaxf(bm, __shfl_xor(bm, 16, 64));
        bm = fmaxf(bm, __shfl_xor(bm, 32, 64));
        const float mn   = fmaxf(m, bm);
        const float corr = __expf(m - mn);
        const float w    = __expf(s - mn);
        m = mn;
        float ls = w;
        ls += __shfl_xor(ls, 8, 64);
        ls += __shfl_xor(ls, 16, 64);
        ls += __shfl_xor(ls, 32, 64);
        l = l * corr + ls;

        const float corrB = __shfl(corr, hB, 64);
        o0*=corrB; o1*=corrB; o2*=corrB; o3*=corrB;
        o4*=corrB; o5*=corrB; o6*=corrB; o7*=corrB;
#pragma unroll
        for (int e = 0; e < 8; ++e) {
            const int   ce    = __shfl(cj, e * 8, 64);
            const float alpha = __shfl(w, e * 8 + hB, 64);
            uint4 vp = *(const uint4*)(Vb + (size_t)ce * HD + lane * 8);
            o0 = fmaf(alpha, bflo(vp.x), o0);
            o1 = fmaf(alpha, bfhi(vp.x), o1);
            o2 = fmaf(alpha, bflo(vp.y), o2);
            o3 = fmaf(alpha, bfhi(vp.y), o3);
            o4 = fmaf(alpha, bflo(vp.z), o4);
            o5 = fmaf(alpha, bfhi(vp.z), o5);
            o6 = fmaf(alpha, bflo(vp.w), o6);
            o7 = fmaf(alpha, bfhi(vp.w), o7);
        }
    }

    const float lB  = __shfl(l, hB, 64);
    const float inv = 1.f / (lB + 1e-16f);
    float4 r0 = {o0*inv, o1*inv, o2*inv, o3*inv};
    float4 r1 = {o4*inv, o5*inv, o6*inv, o7*inv};
    *(float4*)(out + (size_t)r * HD + lane * 8)     = r0;
    *(float4*)(out + (size_t)r * HD + lane * 8 + 4) = r1;
}

// ---------------- launcher ----------------
extern "C" void kernel_launch(void* const* d_in, const int* in_sizes, int n_in,
                              void* d_out, int out_size, void* d_ws, size_t ws_size,
                              hipStream_t stream)
{
    const float* x  = (const float*)d_in[0];
    const int*   ei = (const int*)d_in[1];
    const float* Wq = (const float*)d_in[2];
    const float* Wk = (const float*)d_in[3];
    const float* Wv = (const float*)d_in[4];
    const float* Dm = (const float*)d_in[5];
    float* out = (float*)d_out;

    char* ws = (char*)d_ws;
    bf16* Qb      = (bf16*)(ws + WS_Q);
    bf16* Kb      = (bf16*)(ws + WS_K);
    bf16* Vb      = (bf16*)(ws + WS_V);
    int*  offsets = (int*)(ws + WS_OFFSETS);
    int*  cursor  = (int*)(ws + WS_CURSOR);
    int*  deg     = (int*)(ws + WS_DEG);
    int*  csr_col = (int*)(ws + WS_CSR);
    float* sQ2    = (float*)(ws + WS_SQ2);
    int*  aux     = (int*)(ws + WS_AUX);

    // d_out doubles as scratch for the GEMM inputs; edge_attn rewrites all of
    // d_out at the end of every call, so nothing stale survives.
    bf16* xb = (bf16*)((char*)d_out + DOUT_XB);
    bf16* Wt = (bf16*)((char*)d_out + DOUT_WT);

    const int* row = ei;
    const int* col = ei + N_EDGES;

    hipLaunchKernelGGL(zero_deg_kernel, dim3((N_NODES + 255) / 256), dim3(256), 0, stream, deg);
    hipLaunchKernelGGL(convert_x, dim3(N_PAD * 32 / 256), dim3(256), 0, stream, x, xb);
    hipLaunchKernelGGL(convert_w, dim3((3 * 512 * 256 + 255) / 256), dim3(256), 0, stream,
                       Wq, Wk, Wv, Wt);
    hipLaunchKernelGGL(hist_kernel, dim3((N_EDGES + 255) / 256), dim3(256), 0, stream, row, deg);
    hipLaunchKernelGGL(mfma_qkv, dim3(N_PAD / 128, 4, 3), dim3(256), 0, stream,
                       xb, Wt, Qb, Kb, Vb);
    hipLaunchKernelGGL(scan_local, dim3(SCAN_BLOCKS), dim3(1024), 0, stream, deg, offsets, aux);
    hipLaunchKernelGGL(scan_aux, dim3(1), dim3(64), 0, stream, aux);
    hipLaunchKernelGGL(scan_apply, dim3(SCAN_BLOCKS), dim3(1024), 0, stream, aux, offsets, cursor);
    hipLaunchKernelGGL(scatter_kernel, dim3((N_EDGES + 255) / 256), dim3(256), 0, stream,
                       row, col, cursor, csr_col);
    hipLaunchKernelGGL(sq2_kernel, dim3((N_NODES + 3) / 4), dim3(256), 0, stream, Qb, Dm, sQ2);
    hipLaunchKernelGGL(edge_attn, dim3((N_NODES + 3) / 4), dim3(256), 0, stream,
                       Qb, Kb, Vb, Dm, sQ2, offsets, csr_col, out);
}